// Round 6
// baseline (304.065 us; speedup 1.0000x reference)
//
#include <hip/hip_runtime.h>
#include <math.h>

// Problem constants
#define NROWS   131072          // 4 * 32*32*32
#define NCH     64              // embedding dim / channels
#define NEMB    512             // codebook size
#define CH_STRIDE 32768         // 32*32*32 (stride between channels)
#define B_STRIDE  (64*32768)    // stride between batches
#define Q_ELEMS   8388608       // 4*64*32*32*32

// Which numpy f32 summation order to emulate for A = sum(x^2):
// 1 = AVX512 npyv pairwise (4x16-lane accs, (c0+c1)+(c2+c3), fold 8/4/2/1)
// 0 = scalar 8-accumulator pairwise ((r0+r1)+(r2+r3))+((r4+r5)+(r6+r7))
#define NP_AVX512_SUM 1

// ws layout: [0] double loss_acc ; [16] float esq[512] (= ||e_k||^2, f32)

__global__ __launch_bounds__(64)
void vq_esq(const float* __restrict__ emb, float* __restrict__ esq) {
    int k = blockIdx.x * 64 + threadIdx.x;   // grid 8 x 64 = 512
    if (k < NEMB) {
        const float* e = emb + k * NCH;
        float s = 0.f;
        #pragma unroll
        for (int c = 0; c < NCH; ++c) s = fmaf(e[c], e[c], s);
        esq[k] = s;   // B_k order effects ~1e-11 << d grid 7.6e-6: any order ok
    }
}

__global__ __launch_bounds__(256)
void vq_main(const float* __restrict__ in, const float* __restrict__ emb,
             const float* __restrict__ esq,
             float* __restrict__ out_q, float* __restrict__ out_idx,
             double* __restrict__ loss_acc) {
    int n = blockIdx.x * 256 + threadIdx.x;      // 512 blocks -> exactly NROWS
    int b = n >> 15;
    int s = n & 32767;
    const float* xin = in + b * B_STRIDE + s;

    // Load this row's 64 channel values (coalesced across lanes per channel)
    float x[NCH];
    #pragma unroll
    for (int c = 0; c < NCH; ++c) x[c] = xin[c * CH_STRIDE];

    // ---- A = numpy-f32 sum(x^2) with exact summation order emulation ----
    // Squares are rounded separately (asm barrier stops fma-contraction).
    float A;
#if NP_AVX512_SUM
    {
        float L[16];
        #pragma unroll
        for (int i = 0; i < 16; ++i) {
            float q0 = x[i +  0] * x[i +  0];
            float q1 = x[i + 16] * x[i + 16];
            float q2 = x[i + 32] * x[i + 32];
            float q3 = x[i + 48] * x[i + 48];
            asm volatile("" : "+v"(q0), "+v"(q1), "+v"(q2), "+v"(q3));
            L[i] = (q0 + q1) + (q2 + q3);     // lanewise (c0+c1)+(c2+c3)
        }
        float F[8];
        #pragma unroll
        for (int i = 0; i < 8; ++i) F[i] = L[i] + L[i + 8];   // fold +8
        float G[4];
        #pragma unroll
        for (int i = 0; i < 4; ++i) G[i] = F[i] + F[i + 4];   // fold +4
        float H0 = G[0] + G[2];                                // fold +2
        float H1 = G[1] + G[3];
        A = H0 + H1;                                           // fold +1
    }
#else
    {
        float r[8];
        #pragma unroll
        for (int j = 0; j < 8; ++j) {
            float q = x[j] * x[j];
            asm volatile("" : "+v"(q));
            r[j] = q;
        }
        #pragma unroll
        for (int i = 8; i < 64; i += 8) {
            #pragma unroll
            for (int j = 0; j < 8; ++j) {
                float q = x[i + j] * x[i + j];
                asm volatile("" : "+v"(q));
                r[j] += q;
            }
        }
        A = ((r[0] + r[1]) + (r[2] + r[3])) + ((r[4] + r[5]) + (r[6] + r[7]));
    }
#endif

    // tx = 2*x in place (exact, power of two)
    #pragma unroll
    for (int c = 0; c < NCH; ++c) x[c] = x[c] + x[c];

    // ---- scan: d_k = fl(fl(A + B_k) - C'_k), C' = seq-FMA of (2x).e ----
    // Matches BLAS sgemm's single-accumulator ascending-k chain.
    float m1 = 3.4e38f;
    int   i1 = 0;
    for (int k = 0; k < NEMB; ++k) {
        const float* e = emb + k * NCH;     // wave-uniform -> scalar loads
        float acc = 0.f;
        #pragma unroll
        for (int c = 0; c < NCH; ++c) acc = fmaf(x[c], e[c], acc);
        float t1 = A + esq[k];
        float d  = t1 - acc;
        if (d < m1) { m1 = d; i1 = k; }     // strict <: first-index ties
    }

    // ---- outputs + loss, all from winner i1 ----
    const float* q  = emb + i1 * NCH;
    float*       oq = out_q + b * B_STRIDE + s;
    double rl = 0.0;
    #pragma unroll
    for (int c = 0; c < NCH; ++c) {
        float qc = q[c];
        oq[c * CH_STRIDE] = qc;
        double dd = (double)qc - (double)(0.5f * x[c]);   // x recovered exactly
        rl += dd * dd;
    }
    out_idx[n] = (float)i1;

    // wave-level f64 reduce, one atomic per wave
    #pragma unroll
    for (int off = 32; off; off >>= 1) rl += __shfl_down(rl, off);
    if ((threadIdx.x & 63) == 0) atomicAdd(loss_acc, rl);
}

__global__ void vq_loss_final(const double* __restrict__ loss_acc,
                              float* __restrict__ out_loss) {
    if (threadIdx.x == 0)
        *out_loss = (float)((*loss_acc) * (1.25 / (double)Q_ELEMS));
}

extern "C" void kernel_launch(void* const* d_in, const int* in_sizes, int n_in,
                              void* d_out, int out_size, void* d_ws, size_t ws_size,
                              hipStream_t stream) {
    const float* in  = (const float*)d_in[0];   // [4,64,32,32,32]
    const float* emb = (const float*)d_in[1];   // [512,64]

    float* out_q    = (float*)d_out;            // 8388608
    float* out_loss = out_q + Q_ELEMS;          // 1
    float* out_idx  = out_q + Q_ELEMS + 1;      // 131072

    char*   ws       = (char*)d_ws;
    double* loss_acc = (double*)ws;
    float*  esq      = (float*)(ws + 16);

    hipMemsetAsync(d_ws, 0, 16, stream);
    vq_esq<<<8, 64, 0, stream>>>(emb, esq);
    vq_main<<<NROWS / 256, 256, 0, stream>>>(in, emb, esq, out_q, out_idx,
                                             loss_acc);
    vq_loss_final<<<1, 64, 0, stream>>>(loss_acc, out_loss);
}

// Round 7
// 263.489 us; speedup vs baseline: 1.1540x; 1.1540x over previous
//
#include <hip/hip_runtime.h>
#include <math.h>

// Problem constants
#define NROWS   131072          // 4 * 32*32*32
#define NCH     64              // embedding dim / channels
#define NEMB    512             // codebook size
#define CH_STRIDE 32768         // 32*32*32 (stride between channels)
#define B_STRIDE  (64*32768)    // stride between batches
#define Q_ELEMS   8388608       // 4*64*32*32*32
#define SPLITS  4               // codebook quarters (occupancy)
#define KPQ     (NEMB/SPLITS)   // 128 codewords per quarter

// ws layout: [0] double loss_acc ; [16] float esq[512] ;
//            [4096] u64 parts[NROWS][SPLITS]  (4 MB)

__global__ __launch_bounds__(64)
void vq_esq(const float* __restrict__ emb, float* __restrict__ esq) {
    int k = blockIdx.x * 64 + threadIdx.x;   // grid 8 x 64 = 512
    if (k < NEMB) {
        const float* e = emb + k * NCH;
        float s = 0.f;
        #pragma unroll
        for (int c = 0; c < NCH; ++c) s = fmaf(e[c], e[c], s);
        esq[k] = s;   // B_k order effects ~1e-11 << d grid 7.6e-6: any order ok
    }
}

// Scan: lane = row, e-row wave-uniform (SGPR via s_load), codebook split 4x.
// d_k = fl(fl(A + B_k) - fl(2*acc)), acc = ascending-c seq-FMA of x.e
// == bit-identical to the round-6 passing kernel's chain (x2 scaling exact).
__global__ __launch_bounds__(256, 4)
void vq_scan(const float* __restrict__ in, const float* __restrict__ emb,
             const float* __restrict__ esq,
             unsigned long long* __restrict__ parts) {
    int q      = blockIdx.x & (SPLITS - 1);      // codebook quarter
    int rowblk = blockIdx.x >> 2;                // 0..511
    int n      = rowblk * 256 + threadIdx.x;     // this thread's row
    int b = n >> 15;
    int s = n & 32767;
    const float* xin = in + b * B_STRIDE + s;

    // x row: coalesced across lanes per channel; lives in VGPRs (cap 128)
    float x[NCH];
    #pragma unroll
    for (int c = 0; c < NCH; ++c) x[c] = xin[c * CH_STRIDE];

    // A = numpy-f32 sum(x^2), AVX512 npyv pairwise order (verified passing)
    float A;
    {
        float L[16];
        #pragma unroll
        for (int i = 0; i < 16; ++i) {
            float q0 = x[i +  0] * x[i +  0];
            float q1 = x[i + 16] * x[i + 16];
            float q2 = x[i + 32] * x[i + 32];
            float q3 = x[i + 48] * x[i + 48];
            asm volatile("" : "+v"(q0), "+v"(q1), "+v"(q2), "+v"(q3));
            L[i] = (q0 + q1) + (q2 + q3);
        }
        float F[8];
        #pragma unroll
        for (int i = 0; i < 8; ++i) F[i] = L[i] + L[i + 8];
        float G[4];
        #pragma unroll
        for (int i = 0; i < 4; ++i) G[i] = F[i] + F[i + 4];
        A = (G[0] + G[2]) + (G[1] + G[3]);
    }

    // k-quarter scan; k0 forced into SGPR so e/esq loads are scalar
    int k0 = __builtin_amdgcn_readfirstlane(q * KPQ);
    float m1 = 3.4e38f;
    int   i1 = k0;
    for (int j = 0; j < KPQ; ++j) {
        int k = k0 + j;
        const float* e = emb + k * NCH;          // uniform -> s_load_dwordx16
        float acc = 0.f;
        #pragma unroll
        for (int c = 0; c < NCH; ++c) acc = fmaf(x[c], e[c], acc);
        float t1 = A + esq[k];                   // esq[k] uniform -> s_load
        float d  = t1 - (acc + acc);             // fl(2acc) exact
        bool lt = d < m1;                        // strict <: first-index ties
        m1 = lt ? d : m1;
        i1 = lt ? k : i1;
    }

    // d > 0 always (||x-e||^2 ~ 60) -> f32 bits monotonic; k in low bits
    // makes u64-min give global first-index tie-break.
    unsigned long long pk =
        ((unsigned long long)__float_as_uint(m1) << 32) | (unsigned)i1;
    parts[(unsigned)n * SPLITS + q] = pk;
}

__global__ __launch_bounds__(256)
void vq_finish(const float* __restrict__ in, const float* __restrict__ emb,
               const unsigned long long* __restrict__ parts,
               float* __restrict__ out_q, float* __restrict__ out_idx,
               double* __restrict__ loss_acc) {
    int n = blockIdx.x * 256 + threadIdx.x;
    int b = n >> 15;
    int s = n & 32767;

    // combine quarters: u64 min = (min d, then min k) -> exact first-index
    ulonglong2 pa = *reinterpret_cast<const ulonglong2*>(parts + (unsigned)n * 4);
    ulonglong2 pb = *reinterpret_cast<const ulonglong2*>(parts + (unsigned)n * 4 + 2);
    unsigned long long pk = pa.x;
    if (pa.y < pk) pk = pa.y;
    if (pb.x < pk) pk = pb.x;
    if (pb.y < pk) pk = pb.y;
    int w = (int)(pk & 0xFFFFu);

    const float* xin = in + b * B_STRIDE + s;
    const float* qr  = emb + w * NCH;            // per-lane row, L2-resident
    float*       oq  = out_q + b * B_STRIDE + s;
    double rl = 0.0;
    #pragma unroll
    for (int c = 0; c < NCH; c += 4) {
        float4 qv = *reinterpret_cast<const float4*>(qr + c);
        float x0 = xin[(c + 0) * CH_STRIDE];
        float x1 = xin[(c + 1) * CH_STRIDE];
        float x2 = xin[(c + 2) * CH_STRIDE];
        float x3 = xin[(c + 3) * CH_STRIDE];
        oq[(c + 0) * CH_STRIDE] = qv.x;
        oq[(c + 1) * CH_STRIDE] = qv.y;
        oq[(c + 2) * CH_STRIDE] = qv.z;
        oq[(c + 3) * CH_STRIDE] = qv.w;
        double d0 = (double)qv.x - (double)x0;
        double d1 = (double)qv.y - (double)x1;
        double d2 = (double)qv.z - (double)x2;
        double d3 = (double)qv.w - (double)x3;
        rl += d0 * d0 + d1 * d1 + d2 * d2 + d3 * d3;
    }
    out_idx[n] = (float)w;

    #pragma unroll
    for (int off = 32; off; off >>= 1) rl += __shfl_down(rl, off);
    if ((threadIdx.x & 63) == 0) atomicAdd(loss_acc, rl);
}

__global__ void vq_loss_final(const double* __restrict__ loss_acc,
                              float* __restrict__ out_loss) {
    if (threadIdx.x == 0)
        *out_loss = (float)((*loss_acc) * (1.25 / (double)Q_ELEMS));
}

extern "C" void kernel_launch(void* const* d_in, const int* in_sizes, int n_in,
                              void* d_out, int out_size, void* d_ws, size_t ws_size,
                              hipStream_t stream) {
    const float* in  = (const float*)d_in[0];   // [4,64,32,32,32]
    const float* emb = (const float*)d_in[1];   // [512,64]

    float* out_q    = (float*)d_out;            // 8388608
    float* out_loss = out_q + Q_ELEMS;          // 1
    float* out_idx  = out_q + Q_ELEMS + 1;      // 131072

    char*   ws       = (char*)d_ws;
    double* loss_acc = (double*)ws;
    float*  esq      = (float*)(ws + 16);
    unsigned long long* parts = (unsigned long long*)(ws + 4096);

    hipMemsetAsync(d_ws, 0, 16, stream);
    vq_esq<<<8, 64, 0, stream>>>(emb, esq);
    vq_scan<<<(NROWS / 256) * SPLITS, 256, 0, stream>>>(in, emb, esq, parts);
    vq_finish<<<NROWS / 256, 256, 0, stream>>>(in, emb, parts,
                                               out_q, out_idx, loss_acc);
    vq_loss_final<<<1, 64, 0, stream>>>(loss_acc, out_loss);
}

// Round 8
// 256.458 us; speedup vs baseline: 1.1856x; 1.0274x over previous
//
#include <hip/hip_runtime.h>
#include <math.h>

// Problem constants
#define NROWS   131072          // 4 * 32*32*32
#define NCH     64              // embedding dim / channels
#define NEMB    512             // codebook size
#define CH_STRIDE 32768         // 32*32*32 (stride between channels)
#define B_STRIDE  (64*32768)    // stride between batches
#define Q_ELEMS   8388608       // 4*64*32*32*32
#define SPLITS  4               // codebook quarters (occupancy)
#define KPQ     (NEMB/SPLITS)   // 128 codewords per quarter

// ws layout: [0] double loss_acc ; [16] float esq[512] ;
//            [4096] u64 parts[SPLITS][NROWS]  (4 MB, coalesced layout)

__global__ __launch_bounds__(64)
void vq_esq(const float* __restrict__ emb, float* __restrict__ esq) {
    int k = blockIdx.x * 64 + threadIdx.x;   // grid 8 x 64 = 512
    if (k < NEMB) {
        const float* e = emb + k * NCH;
        float s = 0.f;
        #pragma unroll
        for (int c = 0; c < NCH; ++c) s = fmaf(e[c], e[c], s);
        esq[k] = s;   // B_k order effects ~1e-11 << d grid 7.6e-6: any order ok
    }
}

// Scan: lane = row; codebook quarter staged in LDS (broadcast ds_read,
// conflict-free, no SGPR pressure); x pinned to VGPRs via asm "+v".
// d_k = fl(fl(A + B_k) - fl(2*acc)), acc = ascending-c seq-FMA of x.e
// == bit-identical to the round-6/7 passing chain (operand residency only).
__global__ __launch_bounds__(256, 4)
void vq_scan(const float* __restrict__ in, const float* __restrict__ emb,
             const float* __restrict__ esq,
             unsigned long long* __restrict__ parts) {
    __shared__ float4 lds_e[KPQ * 16];      // 32 KB: quarter, row-major
    __shared__ float  lds_esq[KPQ];         // 512 B

    int q      = blockIdx.x & (SPLITS - 1);      // codebook quarter
    int rowblk = blockIdx.x >> 2;                // 0..511
    int t      = threadIdx.x;
    int k0     = q * KPQ;
    int n      = rowblk * 256 + t;               // this thread's row
    int b = n >> 15;
    int s = n & 32767;
    const float* xin = in + b * B_STRIDE + s;

    // ---- stage quarter into LDS (coalesced 256x16B passes) ----
    const float4* gq = reinterpret_cast<const float4*>(emb + k0 * NCH);
    #pragma unroll
    for (int i = 0; i < 8; ++i)
        lds_e[t + i * 256] = gq[t + i * 256];
    if (t < KPQ) lds_esq[t] = esq[k0 + t];

    // ---- x row (coalesced across lanes per channel), pinned in VGPRs ----
    float x[NCH];
    #pragma unroll
    for (int c = 0; c < NCH; ++c) x[c] = xin[c * CH_STRIDE];
    #pragma unroll
    for (int c = 0; c < NCH; c += 8)
        asm volatile("" : "+v"(x[c]), "+v"(x[c+1]), "+v"(x[c+2]), "+v"(x[c+3]),
                         "+v"(x[c+4]), "+v"(x[c+5]), "+v"(x[c+6]), "+v"(x[c+7]));

    // A = numpy-f32 sum(x^2), AVX512 npyv pairwise order (verified passing)
    float A;
    {
        float L[16];
        #pragma unroll
        for (int i = 0; i < 16; ++i) {
            float q0 = x[i +  0] * x[i +  0];
            float q1 = x[i + 16] * x[i + 16];
            float q2 = x[i + 32] * x[i + 32];
            float q3 = x[i + 48] * x[i + 48];
            asm volatile("" : "+v"(q0), "+v"(q1), "+v"(q2), "+v"(q3));
            L[i] = (q0 + q1) + (q2 + q3);
        }
        float F[8];
        #pragma unroll
        for (int i = 0; i < 8; ++i) F[i] = L[i] + L[i + 8];
        float G[4];
        #pragma unroll
        for (int i = 0; i < 4; ++i) G[i] = F[i] + F[i + 4];
        A = (G[0] + G[2]) + (G[1] + G[3]);
    }

    __syncthreads();

    // ---- quarter scan: all operands VGPR/LDS-broadcast ----
    float m1 = 3.4e38f;
    int   i1 = k0;
    for (int j = 0; j < KPQ; ++j) {
        const float4* er = lds_e + j * 16;       // wave-uniform addr: broadcast
        float acc = 0.f;
        #pragma unroll
        for (int c4 = 0; c4 < 16; ++c4) {
            float4 ev = er[c4];
            acc = fmaf(x[c4 * 4 + 0], ev.x, acc);
            acc = fmaf(x[c4 * 4 + 1], ev.y, acc);
            acc = fmaf(x[c4 * 4 + 2], ev.z, acc);
            acc = fmaf(x[c4 * 4 + 3], ev.w, acc);
        }
        float t1 = A + lds_esq[j];
        float d  = t1 - (acc + acc);             // fl(2acc) exact
        bool lt = d < m1;                        // strict <: first-index ties
        m1 = lt ? d : m1;
        i1 = lt ? (k0 + j) : i1;
    }

    // d > 0 always -> f32 bits monotonic; k in low bits => u64-min is
    // (min d, then min k): exact first-index tie-break across quarters.
    unsigned long long pk =
        ((unsigned long long)__float_as_uint(m1) << 32) | (unsigned)i1;
    parts[(size_t)q * NROWS + n] = pk;           // coalesced (fix 4x write amp)
}

__global__ __launch_bounds__(256)
void vq_finish(const float* __restrict__ in, const float* __restrict__ emb,
               const unsigned long long* __restrict__ parts,
               float* __restrict__ out_q, float* __restrict__ out_idx,
               double* __restrict__ loss_acc) {
    int n = blockIdx.x * 256 + threadIdx.x;
    int b = n >> 15;
    int s = n & 32767;

    // combine quarters: u64 min -> exact first-index winner
    unsigned long long pk = parts[n];
    unsigned long long p1 = parts[(size_t)NROWS + n];
    unsigned long long p2 = parts[(size_t)2 * NROWS + n];
    unsigned long long p3 = parts[(size_t)3 * NROWS + n];
    if (p1 < pk) pk = p1;
    if (p2 < pk) pk = p2;
    if (p3 < pk) pk = p3;
    int w = (int)(pk & 0xFFFFu);

    const float* xin = in + b * B_STRIDE + s;
    const float* qr  = emb + w * NCH;            // per-lane row, L2-resident
    float*       oq  = out_q + b * B_STRIDE + s;
    double rl = 0.0;
    #pragma unroll
    for (int c = 0; c < NCH; c += 4) {
        float4 qv = *reinterpret_cast<const float4*>(qr + c);
        float x0 = xin[(c + 0) * CH_STRIDE];
        float x1 = xin[(c + 1) * CH_STRIDE];
        float x2 = xin[(c + 2) * CH_STRIDE];
        float x3 = xin[(c + 3) * CH_STRIDE];
        oq[(c + 0) * CH_STRIDE] = qv.x;
        oq[(c + 1) * CH_STRIDE] = qv.y;
        oq[(c + 2) * CH_STRIDE] = qv.z;
        oq[(c + 3) * CH_STRIDE] = qv.w;
        double d0 = (double)qv.x - (double)x0;
        double d1 = (double)qv.y - (double)x1;
        double d2 = (double)qv.z - (double)x2;
        double d3 = (double)qv.w - (double)x3;
        rl += d0 * d0 + d1 * d1 + d2 * d2 + d3 * d3;
    }
    out_idx[n] = (float)w;

    #pragma unroll
    for (int off = 32; off; off >>= 1) rl += __shfl_down(rl, off);
    if ((threadIdx.x & 63) == 0) atomicAdd(loss_acc, rl);
}

__global__ void vq_loss_final(const double* __restrict__ loss_acc,
                              float* __restrict__ out_loss) {
    if (threadIdx.x == 0)
        *out_loss = (float)((*loss_acc) * (1.25 / (double)Q_ELEMS));
}

extern "C" void kernel_launch(void* const* d_in, const int* in_sizes, int n_in,
                              void* d_out, int out_size, void* d_ws, size_t ws_size,
                              hipStream_t stream) {
    const float* in  = (const float*)d_in[0];   // [4,64,32,32,32]
    const float* emb = (const float*)d_in[1];   // [512,64]

    float* out_q    = (float*)d_out;            // 8388608
    float* out_loss = out_q + Q_ELEMS;          // 1
    float* out_idx  = out_q + Q_ELEMS + 1;      // 131072

    char*   ws       = (char*)d_ws;
    double* loss_acc = (double*)ws;
    float*  esq      = (float*)(ws + 16);
    unsigned long long* parts = (unsigned long long*)(ws + 4096);

    hipMemsetAsync(d_ws, 0, 16, stream);
    vq_esq<<<8, 64, 0, stream>>>(emb, esq);
    vq_scan<<<(NROWS / 256) * SPLITS, 256, 0, stream>>>(in, emb, esq, parts);
    vq_finish<<<NROWS / 256, 256, 0, stream>>>(in, emb, parts,
                                               out_q, out_idx, loss_acc);
    vq_loss_final<<<1, 64, 0, stream>>>(loss_acc, out_loss);
}